// Round 5
// baseline (175.878 us; speedup 1.0000x reference)
//
#include <hip/hip_runtime.h>
#include <stdint.h>

// Problem constants
#define BATCH 16384
#define INDIM 256
#define DDIM  128
#define NEXP  8
#define ROWS  32          // batch rows per block (2 row-tiles of 16)

typedef __bf16 bfv8  __attribute__((ext_vector_type(8)));   // MFMA A/B frag: 8 bf16 = 4 VGPRs
typedef float  f32x4 __attribute__((ext_vector_type(4)));   // MFMA C/D frag

// ---------------------------------------------------------------------------
// Prep kernel: repack Wa/Wb/Ws (fp32 [8,256,128]) and Gcat (Ga16|Gb16|Gs24 pad
// to 64 rows) into bf16 MFMA B-fragment layout.
//   W frag slot t = (((st*8+e)*8+kt)*8+nt)*64+lane ; elem j = W[i][d] with
//     i = kt*32 + (lane>>4)*8 + j,  d = nt*16 + (lane&15)
//   Flattened: for g = st*64+e*8+kt, frag(nt) lives at g*4096 + nt*512 elems.
// ---------------------------------------------------------------------------
__global__ void prep_kernel(const float* __restrict__ Wa, const float* __restrict__ Wb,
                            const float* __restrict__ Ws, const float* __restrict__ Ga,
                            const float* __restrict__ Gb, const float* __restrict__ Gs,
                            __bf16* __restrict__ wp, __bf16* __restrict__ gp) {
    int t = blockIdx.x * 256 + threadIdx.x;
    const int NW = 3 * 8 * 8 * 8 * 64;   // 98304 W-frag slots
    if (t < NW) {
        int lane = t & 63, nt = (t >> 6) & 7, kt = (t >> 9) & 7, e = (t >> 12) & 7, st = t >> 15;
        const float* W = (st == 0) ? Wa : (st == 1) ? Wb : Ws;
        int d  = nt * 16 + (lane & 15);
        int i0 = kt * 32 + (lane >> 4) * 8;
        __bf16* o = wp + (size_t)t * 8;
#pragma unroll
        for (int j = 0; j < 8; j++)
            o[j] = (__bf16)W[(size_t)(e * 256 + i0 + j) * 128 + d];
    } else if (t < NW + 2048) {
        int t2 = t - NW;
        int lane = t2 & 63, nt = (t2 >> 6) & 3, kt = t2 >> 8;
        int g  = nt * 16 + (lane & 15);
        int k0 = kt * 32 + (lane >> 4) * 8;
        __bf16* o = gp + (size_t)t2 * 8;
#pragma unroll
        for (int j = 0; j < 8; j++) {
            int k = k0 + j;
            float v = 0.f;
            if (g < 16)      v = Ga[g * 256 + k];
            else if (g < 32) v = Gb[(g - 16) * 256 + k];
            else if (g < 56) v = Gs[(g - 32) * 256 + k];
            o[j] = (__bf16)v;
        }
    }
}

// ---------------------------------------------------------------------------
// Main fused kernel. Grid 512 blocks x 512 threads (8 waves) = 2 blocks/CU,
// 16 waves/CU = 4 waves/SIMD at <=128 VGPR (__launch_bounds__(512,4)).
// Block owns 32 batch rows; wave w owns output cols [16w, 16w+16) (nt = w).
// A (x, bf16) staged once in LDS in MFMA A-frag order; B streamed from L2
// through an 8-slot register pipeline (slot = kt, distance 8 => 8 outstanding
// 1KB loads/wave, fine-grained vmcnt).
// ---------------------------------------------------------------------------
__launch_bounds__(512, 4)
__global__ void ple_kernel(const float* __restrict__ xa, const float* __restrict__ xb,
                           const float* __restrict__ xs,
                           const float* __restrict__ ba, const float* __restrict__ bb,
                           const float* __restrict__ bs,
                           const __bf16* __restrict__ wp, const __bf16* __restrict__ gp,
                           float* __restrict__ out) {
    __shared__ __bf16 xlds[3 * 16 * 512];   // 48 KB: frag (st, mt*8+kt) at *512 + lane*8
    __shared__ float  wT[64 * ROWS];        // 8 KB: softmax weights [gate][row]
    __shared__ float  pm[2][ROWS], ps[2][ROWS], cm[ROWS], civ[ROWS];  // s-group partials

    const int tid  = threadIdx.x;
    const int w    = tid >> 6;       // wave id 0..7
    const int lane = tid & 63;
    const int quad = lane >> 4;      // 0..3
    const int l16  = lane & 15;
    const int r0   = blockIdx.x * ROWS;

    // ---- prime B pipeline immediately (overlaps staging + gate phase) ----
    const __bf16* colb = wp + (size_t)w * 512 + (size_t)lane * 8;   // nt = w
    bfv8 cb[8];
#pragma unroll
    for (int i = 0; i < 8; i++)
        cb[i] = *(const bfv8*)(colb + (size_t)i * 4096);            // g = 0..7 (st0,e0)

    // ---- phase 0: stage x (3 streams) into LDS as bf16 A-frags ----
    // 48 frag-groups (st,mt,kt); wave w handles groups w*6 .. w*6+5.
#pragma unroll
    for (int i = 0; i < 6; i++) {
        int gidx = w * 6 + i;
        int st = gidx >> 4, rem = gidx & 15, mt = rem >> 3, kt = rem & 7;
        const float* x = (st == 0) ? xa : (st == 1) ? xb : xs;
        const float* xr = x + (size_t)(r0 + mt * 16 + l16) * INDIM + kt * 32 + quad * 8;
        f32x4 lo = *(const f32x4*)xr;
        f32x4 hi = *(const f32x4*)(xr + 4);
        bfv8 a;
        a[0] = (__bf16)lo[0]; a[1] = (__bf16)lo[1]; a[2] = (__bf16)lo[2]; a[3] = (__bf16)lo[3];
        a[4] = (__bf16)hi[0]; a[5] = (__bf16)hi[1]; a[6] = (__bf16)hi[2]; a[7] = (__bf16)hi[3];
        *(bfv8*)&xlds[(size_t)(st * 16 + mt * 8 + kt) * 512 + lane * 8] = a;
    }
    __syncthreads();

    // ---- phase 1: gate logits (waves 0..3) + softmax ----
    // wave0: xa x Ga (wT rows 0..15), wave1: xb x Gb (16..31),
    // wave2: xs x Gs[0..15] (32..47), wave3: xs x Gs[16..23] (48..55, 8 pad).
    float e_[2][4], mx_[2][4];       // kept across barrier by waves 2,3
    if (w < 4) {
        const int gst = (w < 2) ? w : 2;
        f32x4 acc0 = {0.f, 0.f, 0.f, 0.f}, acc1 = {0.f, 0.f, 0.f, 0.f};
#pragma unroll
        for (int kt = 0; kt < 8; kt++) {
            bfv8 g  = *(const bfv8*)(gp + ((size_t)(kt * 4 + w) * 64 + lane) * 8);
            bfv8 a0 = *(const bfv8*)&xlds[(size_t)(gst * 16 + kt) * 512 + lane * 8];
            bfv8 a1 = *(const bfv8*)&xlds[(size_t)(gst * 16 + 8 + kt) * 512 + lane * 8];
            acc0 = __builtin_amdgcn_mfma_f32_16x16x32_bf16(a0, g, acc0, 0, 0, 0);
            acc1 = __builtin_amdgcn_mfma_f32_16x16x32_bf16(a1, g, acc1, 0, 0, 0);
        }
        float la[2][4];
#pragma unroll
        for (int r = 0; r < 4; r++) { la[0][r] = acc0[r]; la[1][r] = acc1[r]; }
        if (w == 3 && l16 >= 8) {    // pad gate cols 56..63 -> mask out
#pragma unroll
            for (int mt = 0; mt < 2; mt++)
#pragma unroll
                for (int r = 0; r < 4; r++) la[mt][r] = -1e30f;
        }
        // butterfly max over the 16 l16 lanes (masks 1,2,4,8 stay in-quad)
        float mx[2][4];
#pragma unroll
        for (int mt = 0; mt < 2; mt++)
#pragma unroll
            for (int r = 0; r < 4; r++) mx[mt][r] = la[mt][r];
#pragma unroll
        for (int m = 1; m <= 8; m <<= 1)
#pragma unroll
            for (int mt = 0; mt < 2; mt++)
#pragma unroll
                for (int r = 0; r < 4; r++)
                    mx[mt][r] = fmaxf(mx[mt][r], __shfl_xor(mx[mt][r], m));
        float ex[2][4], sm[2][4];
#pragma unroll
        for (int mt = 0; mt < 2; mt++)
#pragma unroll
            for (int r = 0; r < 4; r++) { ex[mt][r] = __expf(la[mt][r] - mx[mt][r]); sm[mt][r] = ex[mt][r]; }
#pragma unroll
        for (int m = 1; m <= 8; m <<= 1)
#pragma unroll
            for (int mt = 0; mt < 2; mt++)
#pragma unroll
                for (int r = 0; r < 4; r++)
                    sm[mt][r] += __shfl_xor(sm[mt][r], m);
        if (w < 2) {
            // complete softmax in-wave; write wT rows w*16 + l16
#pragma unroll
            for (int mt = 0; mt < 2; mt++)
#pragma unroll
                for (int r = 0; r < 4; r++)
                    wT[(w * 16 + l16) * ROWS + mt * 16 + quad * 4 + r] = ex[mt][r] / sm[mt][r];
        } else {
            // save partials; combine across waves 2,3 after barrier
#pragma unroll
            for (int mt = 0; mt < 2; mt++)
#pragma unroll
                for (int r = 0; r < 4; r++) { e_[mt][r] = ex[mt][r]; mx_[mt][r] = mx[mt][r]; }
            if (l16 == 0) {
#pragma unroll
                for (int mt = 0; mt < 2; mt++)
#pragma unroll
                    for (int r = 0; r < 4; r++) {
                        pm[w - 2][mt * 16 + quad * 4 + r] = mx[mt][r];
                        ps[w - 2][mt * 16 + quad * 4 + r] = sm[mt][r];
                    }
            }
        }
    }
    __syncthreads();
    if (tid < ROWS) {
        float m0 = pm[0][tid], m1 = pm[1][tid];
        float M = fmaxf(m0, m1);
        float S = ps[0][tid] * __expf(m0 - M) + ps[1][tid] * __expf(m1 - M);
        cm[tid] = M; civ[tid] = 1.f / S;
    }
    __syncthreads();
    if (w == 2 || w == 3) {
        const int base = (w == 2) ? 32 : 48;
#pragma unroll
        for (int mt = 0; mt < 2; mt++) {
            f32x4 cmv = *(const f32x4*)&cm[mt * 16 + quad * 4];
            f32x4 cvv = *(const f32x4*)&civ[mt * 16 + quad * 4];
#pragma unroll
            for (int r = 0; r < 4; r++)
                wT[(base + l16) * ROWS + mt * 16 + quad * 4 + r] =
                    e_[mt][r] * __expf(mx_[mt][r] - cmv[r]) * cvv[r];
        }
    }
    __syncthreads();

    // ---- phase 2: experts + gated accumulation ----
    float o[3][2][4];                // [out][mt][reg] = 24 VGPRs
#pragma unroll
    for (int oi = 0; oi < 3; oi++)
#pragma unroll
        for (int mt = 0; mt < 2; mt++)
#pragma unroll
            for (int r = 0; r < 4; r++) o[oi][mt][r] = 0.f;

#define FOLD(oi, gbase)                                                       \
    {                                                                         \
        f32x4 wv0 = *(const f32x4*)&wT[(gbase + eb) * ROWS + quad * 4];       \
        f32x4 wv1 = *(const f32x4*)&wT[(gbase + eb) * ROWS + 16 + quad * 4];  \
        _Pragma("unroll")                                                     \
        for (int r = 0; r < 4; r++) {                                         \
            o[oi][0][r] += wv0[r] * acc0[r];                                  \
            o[oi][1][r] += wv1[r] * acc1[r];                                  \
        }                                                                     \
    }

#pragma unroll
    for (int st = 0; st < 3; st++) {
        const float* bias = (st == 0) ? ba : (st == 1) ? bb : bs;
        const __bf16* aB = &xlds[(size_t)(st * 16) * 512 + lane * 8];

#pragma unroll 1
        for (int eb = 0; eb < NEXP; eb++) {
            float b0 = bias[eb * 128 + w * 16 + l16];

            f32x4 acc0 = {0.f, 0.f, 0.f, 0.f}, acc1 = {0.f, 0.f, 0.f, 0.f};
#pragma unroll
            for (int kt = 0; kt < 8; kt++) {
                bfv8 a0 = *(const bfv8*)(aB + (size_t)kt * 512);
                bfv8 a1 = *(const bfv8*)(aB + (size_t)(8 + kt) * 512);
                acc0 = __builtin_amdgcn_mfma_f32_16x16x32_bf16(a0, cb[kt], acc0, 0, 0, 0);
                acc1 = __builtin_amdgcn_mfma_f32_16x16x32_bf16(a1, cb[kt], acc1, 0, 0, 0);
                // prefetch same kt of the NEXT expert (distance 8 steps)
                if (st < 2 || eb < NEXP - 1)
                    cb[kt] = *(const bfv8*)(colb + (size_t)(st * 64 + eb * 8 + kt + 8) * 4096);
            }

#pragma unroll
            for (int r = 0; r < 4; r++) { acc0[r] += b0; acc1[r] += b0; }

            // gate table rows: a:0-15, b:16-31, s:32-55
            if (st == 0)      { FOLD(0, 0);  FOLD(2, 32); }
            else if (st == 1) { FOLD(1, 16); FOLD(2, 40); }
            else              { FOLD(0, 8);  FOLD(1, 24); FOLD(2, 48); }
        }
    }
#undef FOLD

    // ---- epilogue: store 3 outputs; wave w covers cols 16w..16w+15 ----
#pragma unroll
    for (int oi = 0; oi < 3; oi++) {
        float* ob = out + (size_t)oi * BATCH * DDIM;
#pragma unroll
        for (int mt = 0; mt < 2; mt++)
#pragma unroll
            for (int r = 0; r < 4; r++) {
                int row = r0 + mt * 16 + quad * 4 + r;
                ob[(size_t)row * DDIM + w * 16 + l16] = o[oi][mt][r];
            }
    }
}

extern "C" void kernel_launch(void* const* d_in, const int* in_sizes, int n_in,
                              void* d_out, int out_size, void* d_ws, size_t ws_size,
                              hipStream_t stream) {
    const float* xa = (const float*)d_in[0];
    const float* xb = (const float*)d_in[1];
    const float* xs = (const float*)d_in[2];
    const float* Wa = (const float*)d_in[3];
    const float* ba = (const float*)d_in[4];
    const float* Wb = (const float*)d_in[5];
    const float* bb = (const float*)d_in[6];
    const float* Ws = (const float*)d_in[7];
    const float* bs = (const float*)d_in[8];
    const float* Ga = (const float*)d_in[9];
    const float* Gb = (const float*)d_in[10];
    const float* Gs = (const float*)d_in[11];

    __bf16* wp = (__bf16*)d_ws;                 // 1.5 MB packed expert weights
    __bf16* gp = wp + 3 * 8 * 8 * 8 * 64 * 8;   // packed gate matrix

    prep_kernel<<<392, 256, 0, stream>>>(Wa, Wb, Ws, Ga, Gb, Gs, wp, gp);
    ple_kernel<<<BATCH / ROWS, 512, 0, stream>>>(xa, xb, xs, ba, bb, bs, wp, gp, (float*)d_out);
}

// Round 6
// 169.997 us; speedup vs baseline: 1.0346x; 1.0346x over previous
//
#include <hip/hip_runtime.h>
#include <stdint.h>

// Problem constants
#define BATCH 16384
#define INDIM 256
#define DDIM  128
#define NEXP  8
#define ROWS  64          // batch rows per block (4 row-tiles of 16)

typedef __bf16 bfv8  __attribute__((ext_vector_type(8)));   // MFMA A/B frag: 8 bf16 = 4 VGPRs
typedef float  f32x4 __attribute__((ext_vector_type(4)));   // MFMA C/D frag

// ---------------------------------------------------------------------------
// Prep kernel: repack Wa/Wb/Ws (fp32 [8,256,128]) and Gcat (Ga16|Gb16|Gs24 pad
// to 64 rows) into bf16 MFMA B-fragment layout.
//   W frag slot t = (((st*8+e)*8+kt)*8+nt)*64+lane ; elem j = W[i][d] with
//     i = kt*32 + (lane>>4)*8 + j,  d = nt*16 + (lane&15)
//   Flattened: for g = st*64+e*8+kt, frag(nt) lives at g*4096 + nt*512 elems.
// ---------------------------------------------------------------------------
__global__ void prep_kernel(const float* __restrict__ Wa, const float* __restrict__ Wb,
                            const float* __restrict__ Ws, const float* __restrict__ Ga,
                            const float* __restrict__ Gb, const float* __restrict__ Gs,
                            __bf16* __restrict__ wp, __bf16* __restrict__ gp) {
    int t = blockIdx.x * 256 + threadIdx.x;
    const int NW = 3 * 8 * 8 * 8 * 64;   // 98304 W-frag slots
    if (t < NW) {
        int lane = t & 63, nt = (t >> 6) & 7, kt = (t >> 9) & 7, e = (t >> 12) & 7, st = t >> 15;
        const float* W = (st == 0) ? Wa : (st == 1) ? Wb : Ws;
        int d  = nt * 16 + (lane & 15);
        int i0 = kt * 32 + (lane >> 4) * 8;
        __bf16* o = wp + (size_t)t * 8;
#pragma unroll
        for (int j = 0; j < 8; j++)
            o[j] = (__bf16)W[(size_t)(e * 256 + i0 + j) * 128 + d];
    } else if (t < NW + 2048) {
        int t2 = t - NW;
        int lane = t2 & 63, nt = (t2 >> 6) & 3, kt = t2 >> 8;
        int g  = nt * 16 + (lane & 15);
        int k0 = kt * 32 + (lane >> 4) * 8;
        __bf16* o = gp + (size_t)t2 * 8;
#pragma unroll
        for (int j = 0; j < 8; j++) {
            int k = k0 + j;
            float v = 0.f;
            if (g < 16)      v = Ga[g * 256 + k];
            else if (g < 32) v = Gb[(g - 16) * 256 + k];
            else if (g < 56) v = Gs[(g - 32) * 256 + k];
            o[j] = (__bf16)v;
        }
    }
}

// Load A fragments (2 row-tiles x 8 k-tiles) for one x stream, fp32->bf16.
// rb = absolute row base (already includes the wave's 32-row half).
__device__ __forceinline__ void load_afr(const float* __restrict__ x, int rb,
                                         int l16, int quad, bfv8 afr[2][8]) {
#pragma unroll
    for (int mt = 0; mt < 2; mt++) {
        const float* xr = x + (size_t)(rb + mt * 16 + l16) * INDIM;
#pragma unroll
        for (int kt = 0; kt < 8; kt++) {
            f32x4 lo = *(const f32x4*)(xr + kt * 32 + quad * 8);
            f32x4 hi = *(const f32x4*)(xr + kt * 32 + quad * 8 + 4);
            bfv8 a;
            a[0] = (__bf16)lo[0]; a[1] = (__bf16)lo[1]; a[2] = (__bf16)lo[2]; a[3] = (__bf16)lo[3];
            a[4] = (__bf16)hi[0]; a[5] = (__bf16)hi[1]; a[6] = (__bf16)hi[2]; a[7] = (__bf16)hi[3];
            afr[mt][kt] = a;
        }
    }
}

// ---------------------------------------------------------------------------
// Main fused kernel. Grid 256 blocks (1/CU) x 512 threads (8 waves, 2/SIMD).
// Block owns 64 batch rows. Wave (wr=w>>2, wc=w&3) owns rows [32wr,32wr+32),
// cols [32wc, 32wc+32). The wr=0/wr=1 wave pair reads identical B frags a few
// hundred cycles apart -> second read hits XCD L2, so beyond-L2 B traffic is
// 1.5 MB/block x 256 = 384 MB (half of R4/R5 — the L3-BW theory's lever).
// A in registers; B via distance-4 circular register pipeline (fine vmcnt).
// Register audit: afr 64 + cb 32 + o 48 + acc 16 + temps ~30 = ~190 <= 256.
// ---------------------------------------------------------------------------
__launch_bounds__(512, 2)
__global__ void ple_kernel(const float* __restrict__ xa, const float* __restrict__ xb,
                           const float* __restrict__ xs,
                           const float* __restrict__ ba, const float* __restrict__ bb,
                           const float* __restrict__ bs,
                           const __bf16* __restrict__ wp, const __bf16* __restrict__ gp,
                           float* __restrict__ out) {
    __shared__ float lgt[ROWS * 64];   // logits [row][gate] 16 KB
    __shared__ float wT[64 * ROWS];    // softmax weights [gate][row] 16 KB

    const int tid  = threadIdx.x;
    const int w    = tid >> 6;       // wave id 0..7
    const int lane = tid & 63;
    const int quad = lane >> 4;      // 0..3
    const int l16  = lane & 15;
    const int r0   = blockIdx.x * ROWS;

    bfv8 afr[2][8];                  // A frags: 2 row-tiles x 8 k-tiles (64 VGPRs)

    // ---- Phase 1: gate logits via MFMA ----
    // wave w: gate n-tile nt = w>>1 (stream a/b/s/s), row half = (w&1)*32.
    {
        const int nt  = w >> 1;
        const int mh  = (w & 1) * 32;
        const float* x = (nt == 0) ? xa : (nt == 1) ? xb : xs;  // wave-uniform
        load_afr(x, r0 + mh, l16, quad, afr);
        f32x4 acc[2];
#pragma unroll
        for (int mt = 0; mt < 2; mt++) { f32x4 z = {0.f, 0.f, 0.f, 0.f}; acc[mt] = z; }
#pragma unroll
        for (int kt = 0; kt < 8; kt++) {
            bfv8 g = *(const bfv8*)(gp + ((size_t)(kt * 4 + nt) * 64 + lane) * 8);
#pragma unroll
            for (int mt = 0; mt < 2; mt++)
                acc[mt] = __builtin_amdgcn_mfma_f32_16x16x32_bf16(afr[mt][kt], g, acc[mt], 0, 0, 0);
        }
        // gate cols 56..63 are zero-padded in gp; ignored by the softmax below
#pragma unroll
        for (int mt = 0; mt < 2; mt++)
#pragma unroll
            for (int r = 0; r < 4; r++)
                lgt[(mh + mt * 16 + quad * 4 + r) * 64 + nt * 16 + l16] = acc[mt][r];
    }
    __syncthreads();

    // ---- softmax per row, 3 gate groups; store transposed ----
    if (tid < ROWS) {
        const float* L = lgt + tid * 64;
#pragma unroll
        for (int gi = 0; gi < 3; gi++) {
            const int base = (gi == 0) ? 0 : (gi == 1 ? 16 : 32);
            const int cnt  = (gi == 2) ? 24 : 16;
            float m = -1e30f;
            for (int k = 0; k < cnt; k++) m = fmaxf(m, L[base + k]);
            float s = 0.f;
            for (int k = 0; k < cnt; k++) s += __expf(L[base + k] - m);
            float inv = 1.f / s;
            for (int k = 0; k < cnt; k++) wT[(base + k) * ROWS + tid] = __expf(L[base + k] - m) * inv;
        }
    }
    __syncthreads();

    // ---- Phase 2: experts + gated accumulation ----
    const int wr = w >> 2;           // row half 0..1
    const int wc = w & 3;            // col group 0..3
    const int mb = wr * 32;          // local row base

    float o[3][2][2][4];             // [out][mtl][ntl][reg] = 48 VGPRs
#pragma unroll
    for (int oi = 0; oi < 3; oi++)
#pragma unroll
        for (int mt = 0; mt < 2; mt++)
#pragma unroll
            for (int ntl = 0; ntl < 2; ntl++)
#pragma unroll
                for (int r = 0; r < 4; r++) o[oi][mt][ntl][r] = 0.f;

#define FOLD(oi, gbase)                                                                \
    {                                                                                  \
        _Pragma("unroll")                                                              \
        for (int mt = 0; mt < 2; mt++) {                                               \
            f32x4 wv = *(const f32x4*)(wT + (gbase + eb) * ROWS + mb + mt * 16 + quad * 4); \
            _Pragma("unroll")                                                          \
            for (int ntl = 0; ntl < 2; ntl++)                                          \
                _Pragma("unroll")                                                      \
                for (int r = 0; r < 4; r++)                                            \
                    o[oi][mt][ntl][r] += wv[r] * acc[mt][ntl][r];                      \
        }                                                                              \
    }

    // Per-wave column base inside each 4096-elem fragment group (nt = 2wc+ntl).
    const __bf16* colb = wp + (size_t)(2 * wc) * 512 + (size_t)lane * 8;

    bfv8 cb[4][2];                   // circular B buffer: 4 steps x 2 ntl (32 VGPRs)
#pragma unroll
    for (int i = 0; i < 4; i++) {
        cb[i][0] = *(const bfv8*)(colb + (size_t)i * 4096);
        cb[i][1] = *(const bfv8*)(colb + (size_t)i * 4096 + 512);
    }

#pragma unroll
    for (int st = 0; st < 3; st++) {
        const float* x    = (st == 0) ? xa : (st == 1) ? xb : xs;
        const float* bias = (st == 0) ? ba : (st == 1) ? bb : bs;
        load_afr(x, r0 + mb, l16, quad, afr);

#pragma unroll 1
        for (int eb = 0; eb < NEXP; eb++) {
            float b0 = bias[eb * 128 + wc * 32 + l16];
            float b1 = bias[eb * 128 + wc * 32 + 16 + l16];

            f32x4 acc[2][2];
#pragma unroll
            for (int mt = 0; mt < 2; mt++)
#pragma unroll
                for (int ntl = 0; ntl < 2; ntl++) { f32x4 z = {0.f, 0.f, 0.f, 0.f}; acc[mt][ntl] = z; }

#pragma unroll
            for (int kt = 0; kt < 8; kt++) {
                const int sl = kt & 3;
                acc[0][0] = __builtin_amdgcn_mfma_f32_16x16x32_bf16(afr[0][kt], cb[sl][0], acc[0][0], 0, 0, 0);
                acc[1][0] = __builtin_amdgcn_mfma_f32_16x16x32_bf16(afr[1][kt], cb[sl][0], acc[1][0], 0, 0, 0);
                acc[0][1] = __builtin_amdgcn_mfma_f32_16x16x32_bf16(afr[0][kt], cb[sl][1], acc[0][1], 0, 0, 0);
                acc[1][1] = __builtin_amdgcn_mfma_f32_16x16x32_bf16(afr[1][kt], cb[sl][1], acc[1][1], 0, 0, 0);
                // prefetch step g+4 into the slot just consumed
                if (kt < 4 || st < 2 || eb < NEXP - 1) {
                    size_t gpf = (size_t)(st * 64 + eb * 8 + kt + 4) * 4096;
                    cb[sl][0] = *(const bfv8*)(colb + gpf);
                    cb[sl][1] = *(const bfv8*)(colb + gpf + 512);
                }
            }

#pragma unroll
            for (int mt = 0; mt < 2; mt++)
#pragma unroll
                for (int r = 0; r < 4; r++) { acc[mt][0][r] += b0; acc[mt][1][r] += b1; }

            // gate table rows: a:0-15, b:16-31, s:32-55
            // out_a = cat(ea,es): ea->e, es->8+e ; out_b = cat(eb,es): eb->16+e, es->24+e
            // out_s = cat(ea,eb,es): ea->32+e, eb->40+e, es->48+e
            if (st == 0)      { FOLD(0, 0);  FOLD(2, 32); }
            else if (st == 1) { FOLD(1, 16); FOLD(2, 40); }
            else              { FOLD(0, 8);  FOLD(1, 24); FOLD(2, 48); }
        }
    }
#undef FOLD

    // ---- epilogue: store 3 outputs; wave covers rows mb.., cols 32wc.. ----
#pragma unroll
    for (int oi = 0; oi < 3; oi++) {
        float* ob = out + (size_t)oi * BATCH * DDIM;
#pragma unroll
        for (int mt = 0; mt < 2; mt++)
#pragma unroll
            for (int r = 0; r < 4; r++) {
                int row = r0 + mb + mt * 16 + quad * 4 + r;
#pragma unroll
                for (int ntl = 0; ntl < 2; ntl++)
                    ob[(size_t)row * DDIM + wc * 32 + ntl * 16 + l16] = o[oi][mt][ntl][r];
            }
    }
}

extern "C" void kernel_launch(void* const* d_in, const int* in_sizes, int n_in,
                              void* d_out, int out_size, void* d_ws, size_t ws_size,
                              hipStream_t stream) {
    const float* xa = (const float*)d_in[0];
    const float* xb = (const float*)d_in[1];
    const float* xs = (const float*)d_in[2];
    const float* Wa = (const float*)d_in[3];
    const float* ba = (const float*)d_in[4];
    const float* Wb = (const float*)d_in[5];
    const float* bb = (const float*)d_in[6];
    const float* Ws = (const float*)d_in[7];
    const float* bs = (const float*)d_in[8];
    const float* Ga = (const float*)d_in[9];
    const float* Gb = (const float*)d_in[10];
    const float* Gs = (const float*)d_in[11];

    __bf16* wp = (__bf16*)d_ws;                 // 1.5 MB packed expert weights
    __bf16* gp = wp + 3 * 8 * 8 * 8 * 64 * 8;   // packed gate matrix

    prep_kernel<<<392, 256, 0, stream>>>(Wa, Wb, Ws, Ga, Gb, Gs, wp, gp);
    ple_kernel<<<BATCH / ROWS, 512, 0, stream>>>(xa, xb, xs, ba, bb, bs, wp, gp, (float*)d_out);
}